// Round 1
// baseline (2160.075 us; speedup 1.0000x reference)
//
#include <hip/hip_runtime.h>
#include <math.h>

// Problem constants
#define NB   256      // N batch
#define HD   1024     // H
#define ED   512      // E
#define SS   128      // S
#define VV   50257    // V

typedef __attribute__((ext_vector_type(8))) short bf16x8;
typedef __attribute__((ext_vector_type(4))) float f32x4;

__device__ inline unsigned short f2bf(float x) {
  unsigned u = __float_as_uint(x);
  u += 0x7FFF + ((u >> 16) & 1);   // round to nearest even
  return (unsigned short)(u >> 16);
}

__device__ inline float fast_tanh(float x) {
  // tanh(x) = 1 - 2/(e^{2x}+1); saturates correctly for |x| large
  return 1.f - 2.f / (__expf(2.f * x) + 1.f);
}
__device__ inline float fast_sigmoid(float x) {
  return 1.f / (1.f + __expf(-x));
}

// ---------------- Generic MFMA GEMM: C = epi(A @ B) ----------------
// A: fp32 row-major [M][lda] (lda>=K), M multiple of 128, K multiple of 32
// B: fp32 row-major [K][ldb] (cols may be ragged vs Ncols)
#define BM 128
#define BN 128
#define BK 32
#define LP 40   // LDS row pitch in bf16 elements (80B rows: 16B-aligned frag reads)

enum { EPI_BIAS = 0, EPI_RELU = 1, EPI_SIG_ADD = 2, EPI_TANH_MULADD = 3, EPI_SCORE = 4 };

template <int EPI>
__global__ __launch_bounds__(256)
void gemm_k(const float* __restrict__ A, int lda,
            const float* __restrict__ B, int ldb,
            float* __restrict__ C, int ldc,
            int M, int Ncols, int K,
            const float* __restrict__ bias,
            const float* __restrict__ aux1, int ld1,
            const float* __restrict__ aux2, int ld2,
            float* __restrict__ score_out, const float* __restrict__ vw) {
  __shared__ unsigned short As[BM * LP];
  __shared__ unsigned short Bs[BN * LP];

  const int tid = threadIdx.x;
  const int bm0 = blockIdx.x * BM;
  const int bn0 = blockIdx.y * BN;
  const int lane = tid & 63;
  const int w = tid >> 6;
  const int wm = (w >> 1) * 64;
  const int wn = (w & 1) * 64;
  const int lc = lane & 15;
  const int lq = lane >> 4;

  f32x4 acc[4][4];
#pragma unroll
  for (int i = 0; i < 4; i++)
#pragma unroll
    for (int j = 0; j < 4; j++) acc[i][j] = f32x4{0.f, 0.f, 0.f, 0.f};

  const int a_k4 = (tid & 7) * 4;   // k offset 0..28
  const int a_r  = tid >> 3;        // row 0..31
  const int b_n  = tid & 127;       // col 0..127
  const int b_kk = (tid >> 7) * 16; // k base 0 or 16
  const int gcol = bn0 + b_n;
  const bool bcol_ok = (gcol < Ncols);

  for (int k0 = 0; k0 < K; k0 += BK) {
    // ---- stage A (vectorized fp32 loads, inline bf16 convert) ----
#pragma unroll
    for (int i = 0; i < 4; i++) {
      int row = a_r + i * 32;
      const float4 av = *(const float4*)(A + (size_t)(bm0 + row) * lda + (k0 + a_k4));
      ushort4 hv;
      hv.x = f2bf(av.x); hv.y = f2bf(av.y); hv.z = f2bf(av.z); hv.w = f2bf(av.w);
      *(ushort4*)&As[row * LP + a_k4] = hv;
    }
    // ---- stage B transposed: Bs[n][k] (coalesced global, scalar LDS writes) ----
#pragma unroll
    for (int i = 0; i < 16; i++) {
      int k = b_kk + i;
      float v = bcol_ok ? B[(size_t)(k0 + k) * ldb + gcol] : 0.f;
      Bs[b_n * LP + k] = f2bf(v);
    }
    __syncthreads();

    bf16x8 af[4], bfq[4];
#pragma unroll
    for (int s = 0; s < 4; s++)
      af[s] = *(const bf16x8*)&As[(wm + s * 16 + lc) * LP + lq * 8];
#pragma unroll
    for (int s = 0; s < 4; s++)
      bfq[s] = *(const bf16x8*)&Bs[(wn + s * 16 + lc) * LP + lq * 8];

#pragma unroll
    for (int i = 0; i < 4; i++)
#pragma unroll
      for (int j = 0; j < 4; j++)
        acc[i][j] = __builtin_amdgcn_mfma_f32_16x16x32_bf16(af[i], bfq[j], acc[i][j], 0, 0, 0);
    __syncthreads();
  }

  // ---- epilogue ----
  if constexpr (EPI == EPI_SCORE) {
    // score[row] += sum_col tanh(acc + U_b[col] + Wh[row%256][col]) * v_w[col]
#pragma unroll
    for (int i = 0; i < 4; i++) {
#pragma unroll
      for (int r = 0; r < 4; r++) {
        int row = bm0 + wm + i * 16 + lq * 4 + r;
        float p = 0.f;
#pragma unroll
        for (int j = 0; j < 4; j++) {
          int col = bn0 + wn + j * 16 + lc;
          float val = acc[i][j][r] + bias[col] + aux1[(size_t)(row & (NB - 1)) * ld1 + col];
          p += fast_tanh(val) * vw[col];
        }
        p += __shfl_xor(p, 1);
        p += __shfl_xor(p, 2);
        p += __shfl_xor(p, 4);
        p += __shfl_xor(p, 8);
        if (lc == 0) atomicAdd(&score_out[row], p);
      }
    }
  } else {
#pragma unroll
    for (int i = 0; i < 4; i++) {
#pragma unroll
      for (int j = 0; j < 4; j++) {
        int colb = bn0 + wn + j * 16 + lc;
        if (colb < Ncols) {
#pragma unroll
          for (int r = 0; r < 4; r++) {
            int row = bm0 + wm + i * 16 + lq * 4 + r;
            float v = acc[i][j][r] + bias[colb];
            if constexpr (EPI == EPI_RELU) v = fmaxf(v, 0.f);
            if constexpr (EPI == EPI_SIG_ADD) {
              v += aux1[(size_t)row * ld1 + colb];
              v = fast_sigmoid(v);
            }
            if constexpr (EPI == EPI_TANH_MULADD) {
              v += aux2[(size_t)row * ld2 + colb] * aux1[(size_t)row * ld1 + colb];
              v = fast_tanh(v);
            }
            C[(size_t)row * ldc + colb] = v;
          }
        }
      }
    }
  }
}

// ---------------- x gather + score zero-init ----------------
__global__ void init_gather_k(const int* __restrict__ ids, const float* __restrict__ emb,
                              float* __restrict__ acat, float* __restrict__ score) {
  int n = blockIdx.x;
  int t = threadIdx.x;  // 128
  score[n * 128 + t] = 0.f;
  int id = ids[n];
  float4 v = *(const float4*)(emb + (size_t)id * ED + t * 4);
  *(float4*)(acat + (size_t)n * (ED + HD) + t * 4) = v;
}

// ---------------- softmax over S (per batch column n) ----------------
__global__ void softmax_s_k(const float* __restrict__ score, float* __restrict__ attn) {
  int n = blockIdx.x;
  int t = threadIdx.x;  // 64
  float v0 = score[t * NB + n];
  float v1 = score[(t + 64) * NB + n];
  float m = fmaxf(v0, v1);
  for (int d = 1; d < 64; d <<= 1) m = fmaxf(m, __shfl_xor(m, d));
  float e0 = __expf(v0 - m), e1 = __expf(v1 - m);
  float s = e0 + e1;
  for (int d = 1; d < 64; d <<= 1) s += __shfl_xor(s, d);
  float inv = 1.f / s;
  attn[t * NB + n] = e0 * inv;
  attn[(t + 64) * NB + n] = e1 * inv;
}

// ---------------- context = sum_s attn[s,n]*eo[s,n,:] ----------------
__global__ void context_k(const float* __restrict__ attn, const float* __restrict__ eo,
                          float* __restrict__ acat) {
  int n = blockIdx.x;
  int t = threadIdx.x;  // 256
  __shared__ float a_s[SS];
  if (t < SS) a_s[t] = attn[t * NB + n];
  __syncthreads();
  float4 c = make_float4(0.f, 0.f, 0.f, 0.f);
  const float* base = eo + (size_t)n * HD + t * 4;
  for (int s = 0; s < SS; s++) {
    float4 e = *(const float4*)(base + (size_t)s * NB * HD);
    float a = a_s[s];
    c.x += a * e.x; c.y += a * e.y; c.z += a * e.z; c.w += a * e.w;
  }
  *(float4*)(acat + (size_t)n * (ED + HD) + ED + t * 4) = c;
}

// ---------------- GRU combine + LayerNorm ----------------
__global__ void gru_ln_k(const float* __restrict__ hidden, const float* __restrict__ gates,
                         const float* __restrict__ cand, const float* __restrict__ ln_g,
                         const float* __restrict__ ln_b, float* __restrict__ hout) {
  int n = blockIdx.x;
  int t = threadIdx.x;  // 256
  float4 hd = *(const float4*)(hidden + (size_t)n * HD + t * 4);
  float4 z  = *(const float4*)(gates + (size_t)n * (2 * HD) + t * 4);
  float4 cd = *(const float4*)(cand + (size_t)n * HD + t * 4);
  float4 h;
  h.x = (1.f - z.x) * hd.x + z.x * cd.x;
  h.y = (1.f - z.y) * hd.y + z.y * cd.y;
  h.z = (1.f - z.z) * hd.z + z.z * cd.z;
  h.w = (1.f - z.w) * hd.w + z.w * cd.w;
  float sum = h.x + h.y + h.z + h.w;
  float sq  = h.x * h.x + h.y * h.y + h.z * h.z + h.w * h.w;
  for (int d = 1; d < 64; d <<= 1) {
    sum += __shfl_xor(sum, d);
    sq  += __shfl_xor(sq, d);
  }
  __shared__ float s1[4], s2[4];
  int w = t >> 6;
  if ((t & 63) == 0) { s1[w] = sum; s2[w] = sq; }
  __syncthreads();
  sum = s1[0] + s1[1] + s1[2] + s1[3];
  sq  = s2[0] + s2[1] + s2[2] + s2[3];
  float mu = sum * (1.f / HD);
  float var = sq * (1.f / HD) - mu * mu;
  float sc = rsqrtf(var + 1e-5f);
  float4 g4 = *(const float4*)(ln_g + t * 4);
  float4 b4 = *(const float4*)(ln_b + t * 4);
  float4 o;
  o.x = (h.x - mu) * sc * g4.x + b4.x;
  o.y = (h.y - mu) * sc * g4.y + b4.y;
  o.z = (h.z - mu) * sc * g4.z + b4.z;
  o.w = (h.w - mu) * sc * g4.w + b4.w;
  *(float4*)(hout + (size_t)n * HD + t * 4) = o;
}

// ---------------- in-place log_softmax over V ----------------
__global__ void logsoftmax_k(float* __restrict__ p) {
  int n = blockIdx.x;
  float* row = p + (size_t)n * VV;
  int t = threadIdx.x;  // 512
  __shared__ float red[8];
  float m = -3.4e38f;
  for (int c = t; c < VV; c += 512) m = fmaxf(m, row[c]);
  for (int d = 1; d < 64; d <<= 1) m = fmaxf(m, __shfl_xor(m, d));
  if ((t & 63) == 0) red[t >> 6] = m;
  __syncthreads();
  m = red[0];
#pragma unroll
  for (int i = 1; i < 8; i++) m = fmaxf(m, red[i]);
  __syncthreads();
  float s = 0.f;
  for (int c = t; c < VV; c += 512) s += __expf(row[c] - m);
  for (int d = 1; d < 64; d <<= 1) s += __shfl_xor(s, d);
  if ((t & 63) == 0) red[t >> 6] = s;
  __syncthreads();
  s = red[0] + red[1] + red[2] + red[3] + red[4] + red[5] + red[6] + red[7];
  float off = m + logf(s);
  for (int c = t; c < VV; c += 512) row[c] = row[c] - off;
}

extern "C" void kernel_launch(void* const* d_in, const int* in_sizes, int n_in,
                              void* d_out, int out_size, void* d_ws, size_t ws_size,
                              hipStream_t stream) {
  const int*   ids    = (const int*)d_in[0];
  const float* hidden = (const float*)d_in[1];
  const float* eo     = (const float*)d_in[2];
  const float* emb    = (const float*)d_in[3];
  const float* W_w    = (const float*)d_in[4];
  const float* W_b    = (const float*)d_in[5];
  const float* U_w    = (const float*)d_in[6];
  const float* U_b    = (const float*)d_in[7];
  const float* v_w    = (const float*)d_in[8];
  // v_b (d_in[9]) shifts all scores per-n equally -> softmax invariant, skipped
  const float* ih_w   = (const float*)d_in[10];
  const float* ih_b   = (const float*)d_in[11];
  const float* hh_w   = (const float*)d_in[12];
  const float* hh_b   = (const float*)d_in[13];
  const float* cand_w = (const float*)d_in[14];
  const float* cand_b = (const float*)d_in[15];
  const float* hhc_w  = (const float*)d_in[16];
  const float* hhc_b  = (const float*)d_in[17];
  const float* comb_w = (const float*)d_in[18];
  const float* comb_b = (const float*)d_in[19];
  const float* ln_g   = (const float*)d_in[20];
  const float* ln_b   = (const float*)d_in[21];
  const float* out1_w = (const float*)d_in[22];
  const float* out1_b = (const float*)d_in[23];
  const float* out2_w = (const float*)d_in[24];
  const float* out2_b = (const float*)d_in[25];

  float* OUT    = (float*)d_out;
  float* logits = OUT;                         // N*V = 12,865,792 floats
  float* h_out  = OUT + (size_t)NB * VV;       // N*H
  float* attn   = h_out + (size_t)NB * HD;     // S*N

  // Scratch lives inside the logits region (overwritten by the final GEMM).
  float* score = OUT;                 // 32768
  float* Wh    = OUT + 32768;         // 262144
  float* acat  = OUT + 294912;        // 393216 : [x | context] 256x1536
  float* g     = OUT + 688128;        // 131072
  float* P     = OUT + 819200;        // 524288 : g@ih_w + ih_b
  float* gates = OUT + 1343488;       // 524288
  float* Q     = OUT + 1867776;       // 262144 : hidden@hhc_w + hhc_b
  float* cand  = OUT + 2129920;       // 262144
  float* o1    = (float*)d_ws;        // 262144 (must NOT alias logits: GEMM reads it while writing logits)

  init_gather_k<<<NB, 128, 0, stream>>>(ids, emb, acat, score);

  // Wh = hidden @ W_w + W_b
  gemm_k<EPI_BIAS><<<dim3(2, 8), 256, 0, stream>>>(
      hidden, HD, W_w, HD, Wh, HD, NB, HD, HD, W_b, nullptr, 0, nullptr, 0, nullptr, nullptr);

  // score[s*N+n] = sum_j tanh(eo@U_w + U_b + Wh) * v_w   (fused epilogue, atomic)
  gemm_k<EPI_SCORE><<<dim3(SS * NB / BM, HD / BN), 256, 0, stream>>>(
      eo, HD, U_w, HD, nullptr, 0, SS * NB, HD, HD, U_b, Wh, HD, nullptr, 0, score, v_w);

  softmax_s_k<<<NB, 64, 0, stream>>>(score, attn);
  context_k<<<NB, 256, 0, stream>>>(attn, eo, acat);

  // g = relu(acat @ comb_w + comb_b)
  gemm_k<EPI_RELU><<<dim3(2, 4), 256, 0, stream>>>(
      acat, ED + HD, comb_w, ED, g, ED, NB, ED, ED + HD, comb_b, nullptr, 0, nullptr, 0, nullptr, nullptr);

  // P = g @ ih_w + ih_b
  gemm_k<EPI_BIAS><<<dim3(2, 16), 256, 0, stream>>>(
      g, ED, ih_w, 2 * HD, P, 2 * HD, NB, 2 * HD, ED, ih_b, nullptr, 0, nullptr, 0, nullptr, nullptr);

  // gates = sigmoid(hidden @ hh_w + hh_b + P)
  gemm_k<EPI_SIG_ADD><<<dim3(2, 16), 256, 0, stream>>>(
      hidden, HD, hh_w, 2 * HD, gates, 2 * HD, NB, 2 * HD, HD, hh_b, P, 2 * HD, nullptr, 0, nullptr, nullptr);

  // Q = hidden @ hhc_w + hhc_b
  gemm_k<EPI_BIAS><<<dim3(2, 8), 256, 0, stream>>>(
      hidden, HD, hhc_w, HD, Q, HD, NB, HD, HD, hhc_b, nullptr, 0, nullptr, 0, nullptr, nullptr);

  // cand = tanh(g @ cand_w + cand_b + r * Q), r = gates[:, H:]
  gemm_k<EPI_TANH_MULADD><<<dim3(2, 8), 256, 0, stream>>>(
      g, ED, cand_w, HD, cand, HD, NB, HD, ED, cand_b, Q, HD, gates + HD, 2 * HD, nullptr, nullptr);

  gru_ln_k<<<NB, 256, 0, stream>>>(hidden, gates, cand, ln_g, ln_b, h_out);

  // o1 = relu(h_out @ out1_w + out1_b)
  gemm_k<EPI_RELU><<<dim3(2, 8), 256, 0, stream>>>(
      h_out, HD, out1_w, HD, o1, HD, NB, HD, HD, out1_b, nullptr, 0, nullptr, 0, nullptr, nullptr);

  // logits = o1 @ out2_w + out2_b   (ragged N = 50257)
  gemm_k<EPI_BIAS><<<dim3(2, (VV + BN - 1) / BN), 256, 0, stream>>>(
      o1, HD, out2_w, VV, logits, VV, NB, VV, HD, out2_b, nullptr, 0, nullptr, 0, nullptr, nullptr);

  logsoftmax_k<<<NB, 512, 0, stream>>>(logits);
}

// Round 2
// 1046.008 us; speedup vs baseline: 2.0651x; 2.0651x over previous
//
#include <hip/hip_runtime.h>
#include <math.h>

// Problem constants
#define NB   256      // N batch
#define HD   1024     // H
#define ED   512      // E
#define SS   128      // S
#define VV   50257    // V

typedef __attribute__((ext_vector_type(8))) short bf16x8;
typedef __attribute__((ext_vector_type(8))) unsigned short u16x8;
typedef __attribute__((ext_vector_type(4))) float f32x4;

__device__ inline unsigned short f2bf(float x) {
  unsigned u = __float_as_uint(x);
  u += 0x7FFF + ((u >> 16) & 1);   // round to nearest even
  return (unsigned short)(u >> 16);
}

__device__ inline float fast_tanh(float x) {
  return 1.f - 2.f / (__expf(2.f * x) + 1.f);
}
__device__ inline float fast_sigmoid(float x) {
  return 1.f / (1.f + __expf(-x));
}

// ---------------- Generic MFMA GEMM: C = epi(A @ B) ----------------
// A: fp32 row-major [M][lda], M multiple of 128, K multiple of 32, lda%4==0
// B: fp32 row-major [K][ldb]; optional column-split (B2c at col nsplit) and
// row-split (B2k at row krsplit) so two weight matrices fuse into one GEMM.
#define BM 128
#define BN 128
#define BK 32
#define LP 40   // LDS row pitch in bf16 elems: 80B rows; frag b128 reads aligned;
                // B-transpose ds_write_b128 from consecutive-n lanes is conflict-free

enum { EPI_BIAS = 0, EPI_RELU = 1, EPI_SIG = 2, EPI_TANH_MULADD = 3, EPI_SCORE = 4 };

template <int EPI>
__global__ __launch_bounds__(256)
void gemm_k(const float* __restrict__ A, int lda,
            const float* __restrict__ B, int ldb,
            const float* __restrict__ B2c, int ldb2c, int nsplit,
            const float* __restrict__ B2k, int krsplit,
            float* __restrict__ C, int ldc,
            int M, int Ncols, int K,
            const float* __restrict__ bias,
            const float* __restrict__ bias2,
            const float* __restrict__ biasadd,
            const float* __restrict__ aux1, int ld1,
            const float* __restrict__ aux2, int ld2,
            float* __restrict__ score_out, const float* __restrict__ vw) {
  __shared__ unsigned short As[BM * LP];
  __shared__ unsigned short Bs[BN * LP];

  const int tid = threadIdx.x;
  const int bm0 = blockIdx.x * BM;
  const int bn0 = blockIdx.y * BN;
  const int lane = tid & 63;
  const int w = tid >> 6;
  const int wm = (w >> 1) * 64;
  const int wn = (w & 1) * 64;
  const int lc = lane & 15;
  const int lq = lane >> 4;

  f32x4 acc[4][4];
#pragma unroll
  for (int i = 0; i < 4; i++)
#pragma unroll
    for (int j = 0; j < 4; j++) acc[i][j] = f32x4{0.f, 0.f, 0.f, 0.f};

  // A staging: thread -> rows a_r+32i, k-offset a_k4 (float4)
  const int a_k4 = (tid & 7) * 4;
  const int a_r  = tid >> 3;
  // B staging: thread -> col b_n, k-blocks {b_kb, b_kb+2} of 8
  const int b_n  = tid & 127;
  const int b_kb = tid >> 7;  // 0 or 1
  const int gcol = bn0 + b_n;
  const bool bcol_ok = (gcol < Ncols);

  // resolve column-split once per thread
  const float* Bbase; int b_ld; int b_c;
  if (gcol < nsplit) { Bbase = B;   b_ld = ldb;   b_c = gcol; }
  else               { Bbase = B2c; b_ld = ldb2c; b_c = gcol - nsplit; }

  float4 apre[4];
  float  bpre[2][8];

  auto loadA = [&](int k0) {
#pragma unroll
    for (int i = 0; i < 4; i++)
      apre[i] = *(const float4*)(A + (size_t)(bm0 + a_r + i * 32) * lda + (k0 + a_k4));
  };
  auto loadB = [&](int k0) {
#pragma unroll
    for (int t = 0; t < 2; t++) {
      int k = k0 + (b_kb + 2 * t) * 8;
      const float* p = (k < krsplit) ? (Bbase + (size_t)k * b_ld)
                                     : (B2k + (size_t)(k - krsplit) * b_ld);
      p += b_c;
#pragma unroll
      for (int j = 0; j < 8; j++)
        bpre[t][j] = bcol_ok ? p[(size_t)j * b_ld] : 0.f;
    }
  };
  auto storeAB = [&]() {
#pragma unroll
    for (int i = 0; i < 4; i++) {
      ushort4 hv;
      hv.x = f2bf(apre[i].x); hv.y = f2bf(apre[i].y);
      hv.z = f2bf(apre[i].z); hv.w = f2bf(apre[i].w);
      *(ushort4*)&As[(a_r + i * 32) * LP + a_k4] = hv;
    }
#pragma unroll
    for (int t = 0; t < 2; t++) {
      u16x8 h;
#pragma unroll
      for (int j = 0; j < 8; j++) h[j] = f2bf(bpre[t][j]);
      *(u16x8*)&Bs[b_n * LP + (b_kb + 2 * t) * 8] = h;
    }
  };

  loadA(0);
  loadB(0);

  for (int k0 = 0; k0 < K; k0 += BK) {
    storeAB();
    __syncthreads();
    if (k0 + BK < K) { loadA(k0 + BK); loadB(k0 + BK); }  // prefetch overlaps MFMA

    bf16x8 af[4], bfq[4];
#pragma unroll
    for (int s = 0; s < 4; s++)
      af[s] = *(const bf16x8*)&As[(wm + s * 16 + lc) * LP + lq * 8];
#pragma unroll
    for (int s = 0; s < 4; s++)
      bfq[s] = *(const bf16x8*)&Bs[(wn + s * 16 + lc) * LP + lq * 8];

#pragma unroll
    for (int i = 0; i < 4; i++)
#pragma unroll
      for (int j = 0; j < 4; j++)
        acc[i][j] = __builtin_amdgcn_mfma_f32_16x16x32_bf16(af[i], bfq[j], acc[i][j], 0, 0, 0);
    __syncthreads();
  }

  // ---- epilogue ----
  if constexpr (EPI == EPI_SCORE) {
#pragma unroll
    for (int i = 0; i < 4; i++) {
#pragma unroll
      for (int r = 0; r < 4; r++) {
        int row = bm0 + wm + i * 16 + lq * 4 + r;
        float p = 0.f;
#pragma unroll
        for (int j = 0; j < 4; j++) {
          int col = bn0 + wn + j * 16 + lc;
          float val = acc[i][j][r] + bias[col] + aux1[(size_t)(row & (NB - 1)) * ld1 + col];
          p += fast_tanh(val) * vw[col];
        }
        p += __shfl_xor(p, 1);
        p += __shfl_xor(p, 2);
        p += __shfl_xor(p, 4);
        p += __shfl_xor(p, 8);
        if (lc == 0) atomicAdd(&score_out[row], p);
      }
    }
  } else {
#pragma unroll
    for (int i = 0; i < 4; i++) {
#pragma unroll
      for (int j = 0; j < 4; j++) {
        int colb = bn0 + wn + j * 16 + lc;
        if (colb < Ncols) {
          float bb = (colb < nsplit) ? bias[colb] : bias2[colb - nsplit];
          if (biasadd) bb += biasadd[colb];
#pragma unroll
          for (int r = 0; r < 4; r++) {
            int row = bm0 + wm + i * 16 + lq * 4 + r;
            float v = acc[i][j][r] + bb;
            if constexpr (EPI == EPI_RELU) v = fmaxf(v, 0.f);
            if constexpr (EPI == EPI_SIG)  v = fast_sigmoid(v);
            if constexpr (EPI == EPI_TANH_MULADD) {
              v += aux2[(size_t)row * ld2 + colb] * aux1[(size_t)row * ld1 + colb];
              v = fast_tanh(v);
            }
            C[(size_t)row * ldc + colb] = v;
          }
        }
      }
    }
  }
}

// ---------------- x gather + score zero-init ----------------
__global__ void init_gather_k(const int* __restrict__ ids, const float* __restrict__ emb,
                              float* __restrict__ acat, float* __restrict__ score) {
  int n = blockIdx.x;
  int t = threadIdx.x;  // 128
  score[n * 128 + t] = 0.f;
  int id = ids[n];
  float4 v = *(const float4*)(emb + (size_t)id * ED + t * 4);
  *(float4*)(acat + (size_t)n * (ED + HD) + t * 4) = v;
}

// ---------------- copy hidden into gh[:,512:1536] ----------------
__global__ void copy_hidden_k(const float* __restrict__ hidden, float* __restrict__ gh) {
  int n = blockIdx.x;
  int t = threadIdx.x;  // 256
  float4 v = *(const float4*)(hidden + (size_t)n * HD + t * 4);
  *(float4*)(gh + (size_t)n * (ED + HD) + ED + t * 4) = v;
}

// ---------------- softmax over S (per batch column n) ----------------
__global__ void softmax_s_k(const float* __restrict__ score, float* __restrict__ attn) {
  int n = blockIdx.x;
  int t = threadIdx.x;  // 64
  float v0 = score[t * NB + n];
  float v1 = score[(t + 64) * NB + n];
  float m = fmaxf(v0, v1);
  for (int d = 1; d < 64; d <<= 1) m = fmaxf(m, __shfl_xor(m, d));
  float e0 = __expf(v0 - m), e1 = __expf(v1 - m);
  float s = e0 + e1;
  for (int d = 1; d < 64; d <<= 1) s += __shfl_xor(s, d);
  float inv = 1.f / s;
  attn[t * NB + n] = e0 * inv;
  attn[(t + 64) * NB + n] = e1 * inv;
}

// ---------------- context = sum_s attn[s,n]*eo[s,n,:] ----------------
__global__ void context_k(const float* __restrict__ attn, const float* __restrict__ eo,
                          float* __restrict__ acat) {
  int n = blockIdx.x;
  int t = threadIdx.x;  // 256
  __shared__ float a_s[SS];
  if (t < SS) a_s[t] = attn[t * NB + n];
  __syncthreads();
  float4 c = make_float4(0.f, 0.f, 0.f, 0.f);
  const float* base = eo + (size_t)n * HD + t * 4;
  for (int s = 0; s < SS; s++) {
    float4 e = *(const float4*)(base + (size_t)s * NB * HD);
    float a = a_s[s];
    c.x += a * e.x; c.y += a * e.y; c.z += a * e.z; c.w += a * e.w;
  }
  *(float4*)(acat + (size_t)n * (ED + HD) + ED + t * 4) = c;
}

// ---------------- GRU combine + LayerNorm ----------------
__global__ void gru_ln_k(const float* __restrict__ hidden, const float* __restrict__ gates,
                         const float* __restrict__ cand, const float* __restrict__ ln_g,
                         const float* __restrict__ ln_b, float* __restrict__ hout) {
  int n = blockIdx.x;
  int t = threadIdx.x;  // 256
  float4 hd = *(const float4*)(hidden + (size_t)n * HD + t * 4);
  float4 z  = *(const float4*)(gates + (size_t)n * (2 * HD) + t * 4);
  float4 cd = *(const float4*)(cand + (size_t)n * HD + t * 4);
  float4 h;
  h.x = (1.f - z.x) * hd.x + z.x * cd.x;
  h.y = (1.f - z.y) * hd.y + z.y * cd.y;
  h.z = (1.f - z.z) * hd.z + z.z * cd.z;
  h.w = (1.f - z.w) * hd.w + z.w * cd.w;
  float sum = h.x + h.y + h.z + h.w;
  float sq  = h.x * h.x + h.y * h.y + h.z * h.z + h.w * h.w;
  for (int d = 1; d < 64; d <<= 1) {
    sum += __shfl_xor(sum, d);
    sq  += __shfl_xor(sq, d);
  }
  __shared__ float s1[4], s2[4];
  int w = t >> 6;
  if ((t & 63) == 0) { s1[w] = sum; s2[w] = sq; }
  __syncthreads();
  sum = s1[0] + s1[1] + s1[2] + s1[3];
  sq  = s2[0] + s2[1] + s2[2] + s2[3];
  float mu = sum * (1.f / HD);
  float var = sq * (1.f / HD) - mu * mu;
  float sc = rsqrtf(var + 1e-5f);
  float4 g4 = *(const float4*)(ln_g + t * 4);
  float4 b4 = *(const float4*)(ln_b + t * 4);
  float4 o;
  o.x = (h.x - mu) * sc * g4.x + b4.x;
  o.y = (h.y - mu) * sc * g4.y + b4.y;
  o.z = (h.z - mu) * sc * g4.z + b4.z;
  o.w = (h.w - mu) * sc * g4.w + b4.w;
  *(float4*)(hout + (size_t)n * HD + t * 4) = o;
}

// ---------------- in-place log_softmax over V ----------------
__global__ void logsoftmax_k(float* __restrict__ p) {
  int n = blockIdx.x;
  float* row = p + (size_t)n * VV;
  int t = threadIdx.x;  // 512
  __shared__ float red[8];
  float m = -3.4e38f;
  for (int c = t; c < VV; c += 512) m = fmaxf(m, row[c]);
  for (int d = 1; d < 64; d <<= 1) m = fmaxf(m, __shfl_xor(m, d));
  if ((t & 63) == 0) red[t >> 6] = m;
  __syncthreads();
  m = red[0];
#pragma unroll
  for (int i = 1; i < 8; i++) m = fmaxf(m, red[i]);
  __syncthreads();
  float s = 0.f;
  for (int c = t; c < VV; c += 512) s += __expf(row[c] - m);
  for (int d = 1; d < 64; d <<= 1) s += __shfl_xor(s, d);
  if ((t & 63) == 0) red[t >> 6] = s;
  __syncthreads();
  s = red[0] + red[1] + red[2] + red[3] + red[4] + red[5] + red[6] + red[7];
  float off = m + logf(s);
  for (int c = t; c < VV; c += 512) row[c] = row[c] - off;
}

extern "C" void kernel_launch(void* const* d_in, const int* in_sizes, int n_in,
                              void* d_out, int out_size, void* d_ws, size_t ws_size,
                              hipStream_t stream) {
  const int*   ids    = (const int*)d_in[0];
  const float* hidden = (const float*)d_in[1];
  const float* eo     = (const float*)d_in[2];
  const float* emb    = (const float*)d_in[3];
  const float* W_w    = (const float*)d_in[4];
  const float* W_b    = (const float*)d_in[5];
  const float* U_w    = (const float*)d_in[6];
  const float* U_b    = (const float*)d_in[7];
  const float* v_w    = (const float*)d_in[8];
  // v_b (d_in[9]) shifts all scores per-n equally -> softmax invariant, skipped
  const float* ih_w   = (const float*)d_in[10];
  const float* ih_b   = (const float*)d_in[11];
  const float* hh_w   = (const float*)d_in[12];
  const float* hh_b   = (const float*)d_in[13];
  const float* cand_w = (const float*)d_in[14];
  const float* cand_b = (const float*)d_in[15];
  const float* hhc_w  = (const float*)d_in[16];
  const float* hhc_b  = (const float*)d_in[17];
  const float* comb_w = (const float*)d_in[18];
  const float* comb_b = (const float*)d_in[19];
  const float* ln_g   = (const float*)d_in[20];
  const float* ln_b   = (const float*)d_in[21];
  const float* out1_w = (const float*)d_in[22];
  const float* out1_b = (const float*)d_in[23];
  const float* out2_w = (const float*)d_in[24];
  const float* out2_b = (const float*)d_in[25];

  float* OUT    = (float*)d_out;
  float* logits = OUT;                         // N*V
  float* h_out  = OUT + (size_t)NB * VV;       // N*H
  float* attn   = h_out + (size_t)NB * HD;     // S*N

  // Scratch inside the logits region (all consumed before final GEMM writes it)
  float* score = OUT;                 // 32768
  float* WhQ   = OUT + 32768;         // 256x2048 : [Wh | Q]
  float* acat  = OUT + 557056;        // 256x1536 : [x | context]
  float* gh    = OUT + 950272;        // 256x1536 : [g | hidden]
  float* gates = OUT + 1343488;       // 256x2048 : [z | r]
  float* cand  = OUT + 1867776;       // 256x1024
  float* o1    = (float*)d_ws;        // 256x1024 (must not alias logits)

  init_gather_k<<<NB, 128, 0, stream>>>(ids, emb, acat, score);
  copy_hidden_k<<<NB, 256, 0, stream>>>(hidden, gh);

  // [Wh | Q] = hidden @ [W_w | hhc_w] + [W_b | hhc_b]   (column-split B)
  gemm_k<EPI_BIAS><<<dim3(2, 16), 256, 0, stream>>>(
      hidden, HD, W_w, HD, hhc_w, HD, HD, nullptr, 1 << 30,
      WhQ, 2 * HD, NB, 2 * HD, HD, W_b, hhc_b, nullptr,
      nullptr, 0, nullptr, 0, nullptr, nullptr);

  // score[s*N+n] += v . tanh(eo@U_w + U_b + Wh)   (fused epilogue, atomic)
  gemm_k<EPI_SCORE><<<dim3(SS * NB / BM, HD / BN), 256, 0, stream>>>(
      eo, HD, U_w, HD, nullptr, 0, 1 << 30, nullptr, 1 << 30,
      nullptr, 0, SS * NB, HD, HD, U_b, nullptr, nullptr,
      WhQ, 2 * HD, nullptr, 0, score, v_w);

  softmax_s_k<<<NB, 64, 0, stream>>>(score, attn);
  context_k<<<NB, 256, 0, stream>>>(attn, eo, acat);

  // g = relu(acat @ comb_w + comb_b), written into gh[:, :512]
  gemm_k<EPI_RELU><<<dim3(2, 4), 256, 0, stream>>>(
      acat, ED + HD, comb_w, ED, nullptr, 0, 1 << 30, nullptr, 1 << 30,
      gh, ED + HD, NB, ED, ED + HD, comb_b, nullptr, nullptr,
      nullptr, 0, nullptr, 0, nullptr, nullptr);

  // gates = sigmoid([g|hidden] @ [ih_w ; hh_w] + ih_b + hh_b)   (row-split B)
  gemm_k<EPI_SIG><<<dim3(2, 16), 256, 0, stream>>>(
      gh, ED + HD, ih_w, 2 * HD, nullptr, 0, 1 << 30, hh_w, ED,
      gates, 2 * HD, NB, 2 * HD, ED + HD, ih_b, nullptr, hh_b,
      nullptr, 0, nullptr, 0, nullptr, nullptr);

  // cand = tanh(g @ cand_w + cand_b + r * Q)
  gemm_k<EPI_TANH_MULADD><<<dim3(2, 8), 256, 0, stream>>>(
      gh, ED + HD, cand_w, HD, nullptr, 0, 1 << 30, nullptr, 1 << 30,
      cand, HD, NB, HD, ED, cand_b, nullptr, nullptr,
      WhQ + HD, 2 * HD, gates + HD, 2 * HD, nullptr, nullptr);

  gru_ln_k<<<NB, 256, 0, stream>>>(hidden, gates, cand, ln_g, ln_b, h_out);

  // o1 = relu(h_out @ out1_w + out1_b)
  gemm_k<EPI_RELU><<<dim3(2, 8), 256, 0, stream>>>(
      h_out, HD, out1_w, HD, nullptr, 0, 1 << 30, nullptr, 1 << 30,
      o1, HD, NB, HD, HD, out1_b, nullptr, nullptr,
      nullptr, 0, nullptr, 0, nullptr, nullptr);

  // logits = o1 @ out2_w + out2_b
  gemm_k<EPI_BIAS><<<dim3(2, (VV + BN - 1) / BN), 256, 0, stream>>>(
      o1, HD, out2_w, VV, nullptr, 0, 1 << 30, nullptr, 1 << 30,
      logits, VV, NB, VV, HD, out2_b, nullptr, nullptr,
      nullptr, 0, nullptr, 0, nullptr, nullptr);

  logsoftmax_k<<<NB, 512, 0, stream>>>(logits);
}